// Round 4
// baseline (542.365 us; speedup 1.0000x reference)
//
#include <hip/hip_runtime.h>
#include <hip/hip_bf16.h>

#define NTOK 16384
#define HD   4096
#define NE   64
#define KSPLIT 16
#define KS    (HD / KSPLIT)     // 256 K per block
#define NSTEP (KS / 32)         // 8 k-steps
#define SL2   68                // epilogue LDS row stride (floats)

// ws float offsets
#define W2HI_OFF 256                       // 32768 chunks * 8 bf16 = 131072 floats
#define W2LO_OFF (W2HI_OFF + 131072)
#define PART_OFF (W2LO_OFF + 131072)       // 16 * 16384 * 64 floats = 64 MB

typedef __bf16 bf16x8 __attribute__((ext_vector_type(8)));
typedef float  f32x4  __attribute__((ext_vector_type(4)));

__device__ __forceinline__ f32x4 mfma16(bf16x8 a, bf16x8 b, f32x4 c) {
    return __builtin_amdgcn_mfma_f32_16x16x32_bf16(a, b, c, 0, 0, 0);
}

// Split W_gate fp32 -> bf16 hi/lo planes in MFMA-B-fragment chunk order:
// chunk idx = ks*2048 + (s*4+j)*64 + lane, lane = fq*16+fm, expert = j*16+fm,
// k = ks*256 + s*32 + fq*8. Also zeroes the reduction scalars ws[0..129).
__global__ void prep_kernel(const float* __restrict__ Wg, float* __restrict__ ws) {
    const int idx = blockIdx.x * 256 + threadIdx.x;   // 0..32767
    if (blockIdx.x == 0 && threadIdx.x < 129) ws[threadIdx.x] = 0.0f;
    const int ln = idx & 63;
    const int j  = (idx >> 6) & 3;
    const int s  = (idx >> 8) & 7;
    const int ks = idx >> 11;                 // 0..15
    const int e  = j * 16 + (ln & 15);
    const int k  = ks * KS + s * 32 + (ln >> 4) * 8;
    const float* src = Wg + (size_t)e * HD + k;
    float4 q0 = *(const float4*)src;
    float4 q1 = *(const float4*)(src + 4);
    float xs[8] = {q0.x, q0.y, q0.z, q0.w, q1.x, q1.y, q1.z, q1.w};
    bf16x8 hi, lo;
    #pragma unroll
    for (int t = 0; t < 8; ++t) {
        __bf16 h = (__bf16)xs[t];
        hi[t] = h;
        lo[t] = (__bf16)(xs[t] - (float)h);
    }
    *((bf16x8*)((__bf16*)(ws + W2HI_OFF)) + idx) = hi;
    *((bf16x8*)((__bf16*)(ws + W2LO_OFF)) + idx) = lo;
}

// grid 512 = 32 token-blocks x 16 k-slices; block = 512 threads (8 waves).
// Each block: stage 64 KB B tile to LDS once, then each wave streams 64 tokens
// (4 groups of 16) with register-pipelined A loads. No per-iteration barriers.
__global__ __launch_bounds__(512, 4) void gemm_kernel(
    const float* __restrict__ hs, float* __restrict__ ws)
{
    __shared__ bf16x8 sBhi[2048];   // 32 KB
    __shared__ bf16x8 sBlo[2048];   // 32 KB

    const int tid = threadIdx.x;
    const int ks  = blockIdx.x & 15;
    const int tb  = blockIdx.x >> 4;

    // ---- stage B slice (coalesced 16 B/lane)
    {
        const bf16x8* ghi = (const bf16x8*)((const __bf16*)(ws + W2HI_OFF)) + ks * 2048;
        const bf16x8* glo = (const bf16x8*)((const __bf16*)(ws + W2LO_OFF)) + ks * 2048;
        #pragma unroll
        for (int c = 0; c < 4; ++c) {
            sBhi[c * 512 + tid] = ghi[c * 512 + tid];
            sBlo[c * 512 + tid] = glo[c * 512 + tid];
        }
    }
    __syncthreads();

    const int wv   = tid >> 6;
    const int lane = tid & 63;
    const int fm   = lane & 15;
    const int fq   = lane >> 4;
    float* part = ws + PART_OFF + (size_t)ks * (NTOK * 64);

    #pragma unroll 1
    for (int g = 0; g < 4; ++g) {
        const int tok0 = tb * 512 + wv * 64 + g * 16;
        const float* aPtr = hs + (size_t)(tok0 + fm) * HD + ks * KS + fq * 8;

        f32x4 acc[4];
        #pragma unroll
        for (int j = 0; j < 4; ++j) acc[j] = (f32x4){0.f, 0.f, 0.f, 0.f};

        // depth-2 A prefetch, depth-1 B (LDS) prefetch; full unroll -> SSA
        float4 aq[2][2];
        aq[0][0] = *(const float4*)(aPtr);
        aq[0][1] = *(const float4*)(aPtr + 4);
        aq[1][0] = *(const float4*)(aPtr + 32);
        aq[1][1] = *(const float4*)(aPtr + 36);
        bf16x8 bh[2][4], bl[2][4];
        #pragma unroll
        for (int j = 0; j < 4; ++j) {
            bh[0][j] = sBhi[j * 64 + lane];
            bl[0][j] = sBlo[j * 64 + lane];
        }

        #pragma unroll
        for (int s = 0; s < NSTEP; ++s) {
            const int cur = s & 1, nxt = cur ^ 1;
            float4 q0 = aq[cur][0], q1 = aq[cur][1];
            if (s + 2 < NSTEP) {
                aq[cur][0] = *(const float4*)(aPtr + (s + 2) * 32);
                aq[cur][1] = *(const float4*)(aPtr + (s + 2) * 32 + 4);
            }
            if (s + 1 < NSTEP) {
                #pragma unroll
                for (int j = 0; j < 4; ++j) {
                    bh[nxt][j] = sBhi[((s + 1) * 4 + j) * 64 + lane];
                    bl[nxt][j] = sBlo[((s + 1) * 4 + j) * 64 + lane];
                }
            }
            float xs[8] = {q0.x, q0.y, q0.z, q0.w, q1.x, q1.y, q1.z, q1.w};
            bf16x8 ahi, alo;
            #pragma unroll
            for (int t = 0; t < 8; ++t) {
                __bf16 h = (__bf16)xs[t];
                ahi[t] = h;
                alo[t] = (__bf16)(xs[t] - (float)h);
            }
            #pragma unroll
            for (int j = 0; j < 4; ++j) {
                acc[j] = mfma16(ahi, bh[cur][j], acc[j]);
                acc[j] = mfma16(alo, bh[cur][j], acc[j]);
                acc[j] = mfma16(ahi, bl[cur][j], acc[j]);
                acc[j] = mfma16(alo, bl[cur][j], acc[j]);
            }
        }

        // C/D layout: col=fm (expert within 16-block j), row=fq*4+r (token)
        #pragma unroll
        for (int j = 0; j < 4; ++j)
            #pragma unroll
            for (int r = 0; r < 4; ++r)
                part[(size_t)(tok0 + fq * 4 + r) * 64 + j * 16 + fm] = acc[j][r];
    }
}

// grid 1024 x 256: block = 16 tokens; sum 16 k-split partials -> softmax/top-2
__global__ __launch_bounds__(256) void epilogue_kernel(
    float* __restrict__ ws, float* __restrict__ out)
{
    __shared__ float sRed[16 * SL2];
    __shared__ float sInv[16];
    __shared__ float sPp[256];
    __shared__ float sCnt[64];
    __shared__ float sZ;

    const int tid = threadIdx.x;
    const int t0  = blockIdx.x * 16;
    if (tid < 64) sCnt[tid] = 0.0f;
    if (tid == 0) sZ = 0.0f;

    const int g = tid >> 4;     // token 0..15
    const int l = tid & 15;     // 16 lanes/token, 4 experts/lane
    const int tok = t0 + g;
    const float* pbase = ws + PART_OFF + (size_t)tok * 64 + l * 4;
    float4 sv = {0.f, 0.f, 0.f, 0.f};
    #pragma unroll
    for (int k = 0; k < KSPLIT; ++k) {
        float4 v = *(const float4*)(pbase + (size_t)k * (NTOK * 64));
        sv.x += v.x; sv.y += v.y; sv.z += v.z; sv.w += v.w;
    }
    float lv[4] = {sv.x, sv.y, sv.z, sv.w};
    __syncthreads();   // sCnt/sZ zero-init visible before atomics below

    float m = -3.0e38f;
    #pragma unroll
    for (int c = 0; c < 4; ++c) m = fmaxf(m, lv[c]);
    m = fmaxf(m, __shfl_xor(m, 1, 64));
    m = fmaxf(m, __shfl_xor(m, 2, 64));
    m = fmaxf(m, __shfl_xor(m, 4, 64));
    m = fmaxf(m, __shfl_xor(m, 8, 64));

    float* Lrow = &sRed[g * SL2 + l * 4];
    float v1 = -3.0e38f, v2 = -3.0e38f; int i1 = 0, i2 = 0;
    float ssum = 0.0f;
    #pragma unroll
    for (int c = 0; c < 4; ++c) {
        const float val = lv[c]; const int idx = l * 4 + c;
        const float ev = __expf(val - m);
        Lrow[c] = ev;
        ssum += ev;
        if (val > v1) { v2 = v1; i2 = i1; v1 = val; i1 = idx; }
        else if (val > v2) { v2 = val; i2 = idx; }
    }
    ssum += __shfl_xor(ssum, 1, 64);
    ssum += __shfl_xor(ssum, 2, 64);
    ssum += __shfl_xor(ssum, 4, 64);
    ssum += __shfl_xor(ssum, 8, 64);

    #pragma unroll
    for (int s = 1; s <= 8; s <<= 1) {
        const float ov1 = __shfl_xor(v1, s, 64);
        const int   oi1 = __shfl_xor(i1, s, 64);
        const float ov2 = __shfl_xor(v2, s, 64);
        const int   oi2 = __shfl_xor(i2, s, 64);
        float n1, n2; int ni1, ni2;
        const bool ofirst = (ov1 > v1) || (ov1 == v1 && oi1 < i1);
        if (ofirst) {
            n1 = ov1; ni1 = oi1;
            const bool osec = (ov2 > v1) || (ov2 == v1 && oi2 < i1);
            n2 = osec ? ov2 : v1; ni2 = osec ? oi2 : i1;
        } else {
            n1 = v1; ni1 = i1;
            const bool asec = (v2 > ov1) || (v2 == ov1 && i2 < oi1);
            n2 = asec ? v2 : ov1; ni2 = asec ? i2 : oi1;
        }
        v1 = n1; i1 = ni1; v2 = n2; i2 = ni2;
    }

    if (l == 0) {
        const float e1 = __expf(v1 - m), e2 = __expf(v2 - m);
        const float winv = 1.0f / (e1 + e2);
        out[2 * tok]     = e1 * winv;
        out[2 * tok + 1] = e2 * winv;
        out[2 * NTOK + 2 * tok]     = (float)i1;   // indices as f32 (concat promotion)
        out[2 * NTOK + 2 * tok + 1] = (float)i2;
        const float lse = m + __logf(ssum);
        atomicAdd(&sZ, lse * lse);
        atomicAdd(&sCnt[i1], 1.0f);
        atomicAdd(&sCnt[i2], 1.0f);
        sInv[g] = 1.0f / ssum;
    }
    __syncthreads();

    {
        const int e = tid & 63;
        const int q = tid >> 6;
        float p = 0.0f;
        #pragma unroll
        for (int t = 0; t < 4; ++t) {
            const int tk = q * 4 + t;
            p += sRed[tk * SL2 + e] * sInv[tk];
        }
        sPp[q * 64 + e] = p;
    }
    __syncthreads();
    if (tid < 64) {
        const float ps = sPp[tid] + sPp[64 + tid] + sPp[128 + tid] + sPp[192 + tid];
        atomicAdd(&ws[tid], ps);             // sum of probs per expert
        atomicAdd(&ws[64 + tid], sCnt[tid]); // top-2 counts per expert
    }
    if (tid == 0) atomicAdd(&ws[128], sZ);
}

__global__ void finalize_kernel(const float* __restrict__ ws, float* __restrict__ out) {
    const int e = threadIdx.x;   // 64 threads, one wave
    const float P = ws[e] * (1.0f / NTOK);
    const float f = ws[64 + e] * (1.0f / (NTOK * 2));
    float term = f * P;
    #pragma unroll
    for (int s = 32; s >= 1; s >>= 1) term += __shfl_xor(term, s, 64);
    if (e == 0) {
        const float lb = 64.0f * term;
        const float z  = ws[128] * (1.0f / NTOK);
        out[4 * NTOK] = 0.001f * lb + 0.001f * z;
    }
}

extern "C" void kernel_launch(void* const* d_in, const int* in_sizes, int n_in,
                              void* d_out, int out_size, void* d_ws, size_t ws_size,
                              hipStream_t stream) {
    const float* hs = (const float*)d_in[0];
    const float* Wg = (const float*)d_in[1];
    float* out = (float*)d_out;
    float* ws  = (float*)d_ws;

    hipLaunchKernelGGL(prep_kernel, dim3(128), dim3(256), 0, stream, Wg, ws);
    hipLaunchKernelGGL(gemm_kernel, dim3(512), dim3(512), 0, stream, hs, ws);
    hipLaunchKernelGGL(epilogue_kernel, dim3(NTOK / 16), dim3(256), 0, stream, ws, out);
    hipLaunchKernelGGL(finalize_kernel, dim3(1), dim3(64), 0, stream, ws, out);
}

// Round 5
// 448.885 us; speedup vs baseline: 1.2082x; 1.2082x over previous
//
#include <hip/hip_runtime.h>
#include <hip/hip_bf16.h>

#define NTOK 16384
#define HD   4096
#define NE   64
#define SL2  68                 // epilogue LDS row stride (floats)

// ws float offsets: W2 = pre-split W_gate, lane-major fragment order
#define W2HI_OFF 256            // 32768 chunks * 8 bf16 = 131072 floats
#define W2LO_OFF (W2HI_OFF + 131072)

typedef __bf16 bf16x8 __attribute__((ext_vector_type(8)));
typedef float  f32x4  __attribute__((ext_vector_type(4)));

__device__ __forceinline__ f32x4 mfma16(bf16x8 a, bf16x8 b, f32x4 c) {
    return __builtin_amdgcn_mfma_f32_16x16x32_bf16(a, b, c, 0, 0, 0);
}

// W_gate fp32 -> bf16 hi/lo planes, lane-major chunk order:
// chunk idx = ks*2048 + (s*4+j)*64 + lane ; lane = fq*16+fm ;
// expert = j*16+fm ; k = ks*256 + s*32 + fq*8.  (layout verified in R4)
// Also zeroes reduction scalars ws[0..129).
__global__ void prep_kernel(const float* __restrict__ Wg, float* __restrict__ ws) {
    const int idx = blockIdx.x * 256 + threadIdx.x;   // 0..32767
    if (blockIdx.x == 0 && threadIdx.x < 129) ws[threadIdx.x] = 0.0f;
    const int ln = idx & 63;
    const int j  = (idx >> 6) & 3;
    const int s  = (idx >> 8) & 7;
    const int ks = idx >> 11;
    const int e  = j * 16 + (ln & 15);
    const int k  = ks * 256 + s * 32 + (ln >> 4) * 8;
    const float* src = Wg + (size_t)e * HD + k;
    float4 q0 = *(const float4*)src;
    float4 q1 = *(const float4*)(src + 4);
    float xs[8] = {q0.x, q0.y, q0.z, q0.w, q1.x, q1.y, q1.z, q1.w};
    bf16x8 hi, lo;
    #pragma unroll
    for (int t = 0; t < 8; ++t) {
        __bf16 h = (__bf16)xs[t];
        hi[t] = h;
        lo[t] = (__bf16)(xs[t] - (float)h);
    }
    *((bf16x8*)((__bf16*)(ws + W2HI_OFF)) + idx) = hi;
    *((bf16x8*)((__bf16*)(ws + W2LO_OFF)) + idx) = lo;
}

// grid 1024 x 256 thr: block = 16 tokens, 4 waves = 4 K-slices of 1024.
// A: nontemporal direct-to-reg (keeps W2 L2-resident). B: L2-resident W2,
// lane-major coalesced dwordx4. Explicit SSA pipeline: A depth-4, B depth-2.
__global__ __launch_bounds__(256, 3) void router_kernel(
    const float* __restrict__ hs,
    float* __restrict__ out,
    float* __restrict__ ws)
{
    __shared__ float sRed[4 * 16 * SL2];   // per-wave partial logits
    __shared__ float sInv[16];
    __shared__ float sPp[256];
    __shared__ float sCnt[64];
    __shared__ float sZ;

    const int tid  = threadIdx.x;
    const int t0   = blockIdx.x * 16;
    const int wv   = tid >> 6;          // K-slice: [wv*1024, wv*1024+1024)
    const int lane = tid & 63;
    const int fm   = lane & 15;
    const int fq   = lane >> 4;

    if (tid < 64) sCnt[tid] = 0.0f;
    if (tid == 0) sZ = 0.0f;

    const bf16x8* Whi = (const bf16x8*)((const __bf16*)(ws + W2HI_OFF));
    const bf16x8* Wlo = (const bf16x8*)((const __bf16*)(ws + W2LO_OFF));
    const int cbase = wv * 8192 + lane;            // + st*256 + j*64
    const float* aPtr = hs + (size_t)(t0 + fm) * HD + wv * 1024 + fq * 8;

    f32x4 acc[4];
    #pragma unroll
    for (int j = 0; j < 4; ++j) acc[j] = (f32x4){0.f, 0.f, 0.f, 0.f};

    // ---- prologue: A chunks 0..3, B chunks 0..1
    f32x4 aq[4][2];
    #pragma unroll
    for (int d = 0; d < 4; ++d) {
        aq[d][0] = __builtin_nontemporal_load((const f32x4*)(aPtr + d * 32));
        aq[d][1] = __builtin_nontemporal_load((const f32x4*)(aPtr + d * 32 + 4));
    }
    bf16x8 bh[2][4], bl[2][4];
    #pragma unroll
    for (int d = 0; d < 2; ++d)
        #pragma unroll
        for (int j = 0; j < 4; ++j) {
            bh[d][j] = Whi[cbase + d * 256 + j * 64];
            bl[d][j] = Wlo[cbase + d * 256 + j * 64];
        }

    #pragma unroll
    for (int st = 0; st < 32; ++st) {
        const int ab = st & 3, bb = st & 1;
        // consume A chunk into bf16 hi/lo
        f32x4 q0 = aq[ab][0], q1 = aq[ab][1];
        float xs[8] = {q0.x, q0.y, q0.z, q0.w, q1.x, q1.y, q1.z, q1.w};
        bf16x8 ahi, alo;
        #pragma unroll
        for (int t = 0; t < 8; ++t) {
            __bf16 h = (__bf16)xs[t];
            ahi[t] = h;
            alo[t] = (__bf16)(xs[t] - (float)h);
        }
        // A reload depth-4 (clamped tail -> branch-free redundant reload)
        {
            const int nst = (st + 4 < 32) ? (st + 4) : 31;
            aq[ab][0] = __builtin_nontemporal_load((const f32x4*)(aPtr + nst * 32));
            aq[ab][1] = __builtin_nontemporal_load((const f32x4*)(aPtr + nst * 32 + 4));
        }
        // MFMAs on current B buffer
        #pragma unroll
        for (int j = 0; j < 4; ++j) {
            acc[j] = mfma16(ahi, bh[bb][j], acc[j]);
            acc[j] = mfma16(alo, bh[bb][j], acc[j]);
            acc[j] = mfma16(ahi, bl[bb][j], acc[j]);
            acc[j] = mfma16(alo, bl[bb][j], acc[j]);
        }
        // B reload depth-2
        {
            const int nst = (st + 2 < 32) ? (st + 2) : 31;
            #pragma unroll
            for (int j = 0; j < 4; ++j) {
                bh[bb][j] = Whi[cbase + nst * 256 + j * 64];
                bl[bb][j] = Wlo[cbase + nst * 256 + j * 64];
            }
        }
    }

    // ---- combine K-split partials: C/D layout col=fm (expert in j-block), row=fq*4+r
    {
        float* my = &sRed[wv * 16 * SL2];
        #pragma unroll
        for (int j = 0; j < 4; ++j)
            #pragma unroll
            for (int r = 0; r < 4; ++r)
                my[(fq * 4 + r) * SL2 + (j * 16 + fm)] = acc[j][r];
    }
    __syncthreads();
    for (int s = tid; s < 1024; s += 256) {
        const int t = s >> 6, e = s & 63;
        const int o = t * SL2 + e;
        sRed[o] = sRed[o] + sRed[16 * SL2 + o] + sRed[32 * SL2 + o] + sRed[48 * SL2 + o];
    }
    __syncthreads();

    // ---- softmax/top-2: 16 lanes per token, 4 experts per lane (verified R3/R4)
    const int g = tid >> 4;
    const int l = tid & 15;
    float* Lrow = &sRed[g * SL2 + l * 4];
    float lv[4];
    float m = -3.0e38f;
    #pragma unroll
    for (int c = 0; c < 4; ++c) { lv[c] = Lrow[c]; m = fmaxf(m, lv[c]); }
    m = fmaxf(m, __shfl_xor(m, 1, 64));
    m = fmaxf(m, __shfl_xor(m, 2, 64));
    m = fmaxf(m, __shfl_xor(m, 4, 64));
    m = fmaxf(m, __shfl_xor(m, 8, 64));

    float v1 = -3.0e38f, v2 = -3.0e38f; int i1 = 0, i2 = 0;
    float ssum = 0.0f;
    #pragma unroll
    for (int c = 0; c < 4; ++c) {
        const float val = lv[c]; const int idx = l * 4 + c;
        const float ev = __expf(val - m);
        Lrow[c] = ev;
        ssum += ev;
        if (val > v1) { v2 = v1; i2 = i1; v1 = val; i1 = idx; }
        else if (val > v2) { v2 = val; i2 = idx; }
    }
    ssum += __shfl_xor(ssum, 1, 64);
    ssum += __shfl_xor(ssum, 2, 64);
    ssum += __shfl_xor(ssum, 4, 64);
    ssum += __shfl_xor(ssum, 8, 64);

    #pragma unroll
    for (int s = 1; s <= 8; s <<= 1) {
        const float ov1 = __shfl_xor(v1, s, 64);
        const int   oi1 = __shfl_xor(i1, s, 64);
        const float ov2 = __shfl_xor(v2, s, 64);
        const int   oi2 = __shfl_xor(i2, s, 64);
        float n1, n2; int ni1, ni2;
        const bool ofirst = (ov1 > v1) || (ov1 == v1 && oi1 < i1);
        if (ofirst) {
            n1 = ov1; ni1 = oi1;
            const bool osec = (ov2 > v1) || (ov2 == v1 && oi2 < i1);
            n2 = osec ? ov2 : v1; ni2 = osec ? oi2 : i1;
        } else {
            n1 = v1; ni1 = i1;
            const bool asec = (v2 > ov1) || (v2 == ov1 && i2 < oi1);
            n2 = asec ? v2 : ov1; ni2 = asec ? i2 : oi1;
        }
        v1 = n1; i1 = ni1; v2 = n2; i2 = ni2;
    }

    if (l == 0) {
        const float e1 = __expf(v1 - m), e2 = __expf(v2 - m);
        const float winv = 1.0f / (e1 + e2);
        const int token = t0 + g;
        out[2 * token]     = e1 * winv;
        out[2 * token + 1] = e2 * winv;
        out[2 * NTOK + 2 * token]     = (float)i1;   // indices as f32 (concat promotion)
        out[2 * NTOK + 2 * token + 1] = (float)i2;
        const float lse = m + __logf(ssum);
        atomicAdd(&sZ, lse * lse);
        atomicAdd(&sCnt[i1], 1.0f);
        atomicAdd(&sCnt[i2], 1.0f);
        sInv[g] = 1.0f / ssum;
    }
    __syncthreads();

    // ---- per-expert prob sums over 16 tokens, then global atomics
    {
        const int e = tid & 63;
        const int q = tid >> 6;
        float p = 0.0f;
        #pragma unroll
        for (int t = 0; t < 4; ++t) {
            const int tk = q * 4 + t;
            p += sRed[tk * SL2 + e] * sInv[tk];
        }
        sPp[q * 64 + e] = p;
    }
    __syncthreads();
    if (tid < 64) {
        const float ps = sPp[tid] + sPp[64 + tid] + sPp[128 + tid] + sPp[192 + tid];
        atomicAdd(&ws[tid], ps);             // sum of probs per expert
        atomicAdd(&ws[64 + tid], sCnt[tid]); // top-2 counts per expert
    }
    if (tid == 0) atomicAdd(&ws[128], sZ);
}

__global__ void finalize_kernel(const float* __restrict__ ws, float* __restrict__ out) {
    const int e = threadIdx.x;   // 64 threads, one wave
    const float P = ws[e] * (1.0f / NTOK);
    const float f = ws[64 + e] * (1.0f / (NTOK * 2));
    float term = f * P;
    #pragma unroll
    for (int s = 32; s >= 1; s >>= 1) term += __shfl_xor(term, s, 64);
    if (e == 0) {
        const float lb = 64.0f * term;
        const float z  = ws[128] * (1.0f / NTOK);
        out[4 * NTOK] = 0.001f * lb + 0.001f * z;
    }
}

extern "C" void kernel_launch(void* const* d_in, const int* in_sizes, int n_in,
                              void* d_out, int out_size, void* d_ws, size_t ws_size,
                              hipStream_t stream) {
    const float* hs = (const float*)d_in[0];
    const float* Wg = (const float*)d_in[1];
    float* out = (float*)d_out;
    float* ws  = (float*)d_ws;

    hipLaunchKernelGGL(prep_kernel, dim3(128), dim3(256), 0, stream, Wg, ws);
    hipLaunchKernelGGL(router_kernel, dim3(NTOK / 16), dim3(256), 0, stream, hs, out, ws);
    hipLaunchKernelGGL(finalize_kernel, dim3(1), dim3(64), 0, stream, ws, out);
}